// Round 6
// baseline (1187.574 us; speedup 1.0000x reference)
//
#include <hip/hip_runtime.h>
#include <hip/hip_bf16.h>
#include <cstdint>

// sincKAN: 3 layers. B=1024, features 256->512->512->256, LEN_H=2, DEGREE+1=65.
// Kaug = fi*131 (per input i: h0 d0..64 | h1 d0..64 | skip slot = x_i).
// y[b,o] = sum_k A[b,k]*Bt[o,k] + beta[o].
// R6: split-bf16 precision. v = v_hi + v_lo (two bf16, residual ~2^-18 rel);
// GEMM computes hi*hi + lo*hi + hi*lo as 3 MFMA passes (layers 0,1) to kill
// the chaotic amplification (~500-1000x) of layer-0/1 quantization noise that
// produced the persistent absmax~56. Layer 2: single hi pass (noise unamplified).

#define PI_F 3.14159265358979323846f

typedef float floatx4 __attribute__((ext_vector_type(4)));
typedef __bf16 bf16x8 __attribute__((ext_vector_type(8)));

// global -> LDS direct DMA, 16B per lane (lane-contiguous dest, per m104/m108).
#define GLOAD_LDS16(gp, lp)                                                    \
  __builtin_amdgcn_global_load_lds(                                            \
      (const __attribute__((address_space(1))) void*)(uintptr_t)(const void*)(gp), \
      (__attribute__((address_space(3))) void*)(uint32_t)(uintptr_t)(void*)(lp),   \
      16, 0, 0)

// ---------------------------------------------------------------------------
// repack: coeffs (fi,fo,2,65) + alpha (fi,fo) -> Bhi/Blo (fo x Kaug) bf16 pair
__global__ __launch_bounds__(256) void repack_kernel(
    const float* __restrict__ coeffs, const float* __restrict__ alpha,
    __hip_bfloat16* __restrict__ Bhi, __hip_bfloat16* __restrict__ Blo,
    int fo, int Kaug, int writeLo)
{
  int o = blockIdx.y;
  int r = blockIdx.x * 256 + threadIdx.x;   // k index within Kaug (grid exact)
  int i = r / 131;
  int j = r - i * 131;
  float v;
  if (j == 130) {
    v = alpha[(size_t)i * fo + o];
  } else {
    int h1 = (j >= 65) ? 1 : 0;
    int d  = j - (h1 ? 65 : 0);
    v = coeffs[(((size_t)i * fo + o) * 2 + h1) * 65 + d];
  }
  __hip_bfloat16 hb = __float2bfloat16(v);
  Bhi[(size_t)o * Kaug + r] = hb;
  if (writeLo)
    Blo[(size_t)o * Kaug + r] = __float2bfloat16(v - __bfloat162float(hb));
}

// ---------------------------------------------------------------------------
// act: Xin (MB x fi) fp32 -> Ahi/Alo (MB x Kaug) bf16 pair, chunk-local.
// Pole-safe sinc: z = {4,8}*tanh(t); n = rint(z), f = z-n (exact);
// sinc(z+kk) = (-1)^(n+kk) * sin(pi f)/(pi (z+kk)).  s carries (-1)^n.
__global__ __launch_bounds__(256) void act_kernel(
    const float* __restrict__ Xin, __hip_bfloat16* __restrict__ Ahi,
    __hip_bfloat16* __restrict__ Alo, int first, int writeLo)
{
  __shared__ float sm[256][5];
  int tid = threadIdx.x;
  int p0  = blockIdx.x * 256;   // first (b,i) pair of this block (chunk-local)
  {
    float x  = Xin[p0 + tid];
    float t  = first ? tanhf(x) : x;   // layer-0 normalizer
    float xa = tanhf(t);
    float z0 = 4.0f * xa, z1 = 8.0f * xa;   // exact (pow2 scale, h=1/4,1/8)
    float n0 = rintf(z0), n1 = rintf(z1);
    float s0 = sinf(PI_F * (z0 - n0)) * (1.0f / PI_F);
    float s1 = sinf(PI_F * (z1 - n1)) * (1.0f / PI_F);
    if (((int)n0) & 1) s0 = -s0;
    if (((int)n1) & 1) s1 = -s1;
    sm[tid][0] = t;
    sm[tid][1] = z0;
    sm[tid][2] = s0;
    sm[tid][3] = z1;
    sm[tid][4] = s1;
  }
  __syncthreads();
  size_t base = (size_t)p0 * 131;
  for (int e = tid; e < 256 * 131; e += 256) {
    int li = e / 131;
    int j  = e - li * 131;
    float t = sm[li][0];
    bool h1 = (j >= 65);
    int d   = h1 ? (j - 65) : j;
    float z = h1 ? sm[li][3] : sm[li][1];
    float s = h1 ? sm[li][4] : sm[li][2];
    int kk  = d - 32;
    float den = z + (float)kk;
    float v = s / den;
    if (kk & 1) v = -v;
    if (den == 0.0f) v = 1.0f;   // sinc(0) = 1 (sign: n=-kk, parity cancels)
    if (j == 130)    v = t;      // skip-connection slot
    __hip_bfloat16 hb = __float2bfloat16(v);
    Ahi[base + e] = hb;
    if (writeLo)
      Alo[base + e] = __float2bfloat16(v - __bfloat162float(hb));
  }
}

// ---------------------------------------------------------------------------
// gemm: C[m,n] = sum over nterms passes of Asel[m,k]*Bsel[n,k]; split-K over
// the extended step space S = nterms*totalSteps (term-major).
// term 0: Ahi*Bhi; term 1: Alo*Bhi; term 2: Ahi*Blo.
// 128x128 tile, BK=64, 4 waves (2x2 of 64x64), 16x16x32 MFMA. m97 plain LDS.
__global__ __launch_bounds__(256, 2) void gemm_bf16_splitk(
    const __hip_bfloat16* __restrict__ Ahi, const __hip_bfloat16* __restrict__ Alo,
    const __hip_bfloat16* __restrict__ Bhi, const __hip_bfloat16* __restrict__ Blo,
    float* __restrict__ Cpart,              // splitk x MB x N
    int N, int Kaug, int totalSteps, int splitk, int tilesN, int MBN, int nterms)
{
  __shared__ __align__(16) ushort As[128 * 64];
  __shared__ __align__(16) ushort Bs[128 * 64];

  int bx    = blockIdx.x;
  int split = bx % splitk;
  int tile  = bx / splitk;
  int tm = tile / tilesN;
  int tn = tile - tm * tilesN;
  int S  = nterms * totalSteps;
  int s0 = (int)(((long long)split * S) / splitk);
  int s1 = (int)(((long long)(split + 1) * S) / splitk);

  int tid  = threadIdx.x;
  int lane = tid & 63;
  int wave = tid >> 6;
  int wm = (wave >> 1) * 64;
  int wn = (wave & 1) * 64;

  floatx4 acc[4][4];
#pragma unroll
  for (int i = 0; i < 4; i++)
#pragma unroll
    for (int j = 0; j < 4; j++) acc[i][j] = floatx4{0.f, 0.f, 0.f, 0.f};

  for (int term = 0; term < nterms; ++term) {
    int base = term * totalSteps;
    int t0 = s0 - base; if (t0 < 0) t0 = 0;
    int t1 = s1 - base; if (t1 > totalSteps) t1 = totalSteps;
    if (t0 >= t1) continue;

    const ushort* Ag = (const ushort*)((term == 1) ? Alo : Ahi)
                       + (size_t)tm * 128 * Kaug;
    const ushort* Bg = (const ushort*)((term == 2) ? Blo : Bhi)
                       + (size_t)tn * 128 * Kaug;

    for (int s = t0; s < t1; ++s) {
      int k0 = s * 64;
#pragma unroll
      for (int r = 0; r < 4; ++r) {            // stage A tile (128 rows x 64 k)
        int c   = tid + 256 * r;
        int row = c >> 3;
        int kc  = c & 7;
        GLOAD_LDS16(Ag + (size_t)row * Kaug + k0 + kc * 8, &As[c * 8]);
      }
#pragma unroll
      for (int r = 0; r < 4; ++r) {            // stage B tile (128 n-rows x 64 k)
        int c   = tid + 256 * r;
        int row = c >> 3;
        int kc  = c & 7;
        GLOAD_LDS16(Bg + (size_t)row * Kaug + k0 + kc * 8, &Bs[c * 8]);
      }
      __syncthreads();

#pragma unroll
      for (int q = 0; q < 2; ++q) {             // two K=32 MFMA steps per BK=64
        bf16x8 af[4], bf[4];
        int rsub = lane & 15;
        int qc   = q * 4 + (lane >> 4);
#pragma unroll
        for (int t = 0; t < 4; ++t) {
          int row = wm + t * 16 + rsub;
          af[t] = *(const bf16x8*)&As[(row * 8 + qc) * 8];
        }
#pragma unroll
        for (int t = 0; t < 4; ++t) {
          int row = wn + t * 16 + rsub;
          bf[t] = *(const bf16x8*)&Bs[(row * 8 + qc) * 8];
        }
#pragma unroll
        for (int i = 0; i < 4; ++i)
#pragma unroll
          for (int j = 0; j < 4; ++j)
            acc[i][j] = __builtin_amdgcn_mfma_f32_16x16x32_bf16(
                af[i], bf[j], acc[i][j], 0, 0, 0);
      }
      __syncthreads();
    }
  }

  // epilogue: C/D layout col = lane&15, row = (lane>>4)*4 + reg  [m89-verified]
  float* Cp = Cpart + (size_t)split * MBN;
  int mrow0 = tm * 128 + wm + (lane >> 4) * 4;
  int ncol  = tn * 128 + wn + (lane & 15);
#pragma unroll
  for (int i = 0; i < 4; ++i) {
#pragma unroll
    for (int r = 0; r < 4; ++r) {
      int m = mrow0 + i * 16 + r;
      float* dst = Cp + (size_t)m * N + ncol;
#pragma unroll
      for (int j = 0; j < 4; ++j) dst[j * 16] = acc[i][j][r];
    }
  }
}

// ---------------------------------------------------------------------------
// reduce split-K partials + beta -> fp32 (intermediate layers AND final out)
__global__ __launch_bounds__(256) void reduce_f32_kernel(
    const float4* __restrict__ Cp, const float* __restrict__ beta,
    float* __restrict__ Xout, int MN4, int N4mask, int splits)
{
  int e = blockIdx.x * 256 + threadIdx.x;
  if (e >= MN4) return;
  float4 sum = Cp[e];
  for (int s = 1; s < splits; ++s) {
    float4 v = Cp[(size_t)s * MN4 + e];
    sum.x += v.x; sum.y += v.y; sum.z += v.z; sum.w += v.w;
  }
  int n0 = (e & N4mask) * 4;
  sum.x += beta[n0]; sum.y += beta[n0 + 1];
  sum.z += beta[n0 + 2]; sum.w += beta[n0 + 3];
  ((float4*)Xout)[e] = sum;
}

// ---------------------------------------------------------------------------
extern "C" void kernel_launch(void* const* d_in, const int* in_sizes, int n_in,
                              void* d_out, int out_size, void* d_ws, size_t ws_size,
                              hipStream_t stream)
{
  const float* x = (const float*)d_in[0];
  const float* coeffs[3] = {(const float*)d_in[1], (const float*)d_in[4], (const float*)d_in[7]};
  const float* alpha[3]  = {(const float*)d_in[2], (const float*)d_in[5], (const float*)d_in[8]};
  const float* beta[3]   = {(const float*)d_in[3], (const float*)d_in[6], (const float*)d_in[9]};

  const size_t KMAX  = 67072;                    // 512*131
  const size_t needB = 2ull * 512 * KMAX * 2;    // Bhi+Blo = 137,363,456
  const size_t needX = 2ull * 1024 * 512 * 4;    // 4 MB
  const size_t needC = 33554432;                 // 32 MB partials

  // batch chunk MB (A needs MB*KMAX*4 bytes for hi+lo), deterministic per call
  int MB = 128;
  for (int cand = 1024; cand >= 128; cand >>= 1) {
    if ((size_t)cand * KMAX * 4 + needB + needX + needC <= ws_size) { MB = cand; break; }
  }
  int nchunks = 1024 / MB;

  char* ws = (char*)d_ws;
  __hip_bfloat16* Ahi = (__hip_bfloat16*)ws;
  __hip_bfloat16* Alo = Ahi + (size_t)MB * KMAX;
  __hip_bfloat16* Bhi = (__hip_bfloat16*)(ws + (size_t)MB * KMAX * 4);
  __hip_bfloat16* Blo = Bhi + 512 * KMAX;
  float* X1    = (float*)((char*)Bhi + needB);
  float* X2    = X1 + 1024 * 512;
  float* Cpart = X2 + 1024 * 512;

  const int fis[3]  = {256, 512, 512};
  const int fos[3]  = {512, 512, 256};
  const int trm[3]  = {3, 3, 1};   // split-bf16 for layers 0,1; plain for 2

  const float* Xl = x;
  for (int l = 0; l < 3; ++l) {
    int fi = fis[l], fo = fos[l];
    int Kaug = fi * 131;            // 33536 / 67072 — divisible by 256
    int totalSteps = Kaug / 64;
    int tilesN = fo / 128;
    int sk = 8388608 / (MB * fo);   // grid ≈512 blocks, Cpart = 32 MB
    int nterms = trm[l];

    repack_kernel<<<dim3(Kaug / 256, fo), 256, 0, stream>>>(
        coeffs[l], alpha[l], Bhi, Blo, fo, Kaug, nterms > 1 ? 1 : 0);

    float* Xout_f = (l == 0) ? X1 : (l == 1 ? X2 : (float*)d_out);
    for (int c = 0; c < nchunks; ++c) {
      int mb0 = c * MB;
      act_kernel<<<(MB * fi) / 256, 256, 0, stream>>>(
          Xl + (size_t)mb0 * fi, Ahi, Alo, l == 0 ? 1 : 0, nterms > 1 ? 1 : 0);
      gemm_bf16_splitk<<<(MB / 128) * tilesN * sk, 256, 0, stream>>>(
          Ahi, Alo, Bhi, Blo, Cpart, fo, Kaug, totalSteps, sk, tilesN,
          MB * fo, nterms);
      int MN4 = MB * fo / 4;
      reduce_f32_kernel<<<(MN4 + 255) / 256, 256, 0, stream>>>(
          (const float4*)Cpart, beta[l],
          Xout_f + (size_t)mb0 * fo, MN4, fo / 4 - 1, sk);
    }
    Xl = Xout_f;
  }
}

// Round 7
// 1092.541 us; speedup vs baseline: 1.0870x; 1.0870x over previous
//
#include <hip/hip_runtime.h>
#include <hip/hip_bf16.h>
#include <cstdint>

// sincKAN: 3 layers. B=1024, features 256->512->512->256, LEN_H=2, DEGREE+1=65.
// Kaug = fi*131 (per input i: h0 d0..64 | h1 d0..64 | skip slot = x_i).
// Split-bf16 (hi/lo) GEMM: hi*hi + lo*hi + hi*lo for layers 0,1 (kills chaotic
// amplification of quantization noise); layer 2 hi-only. PASSED R6 @ absmax 2.09.
// R7 perf deltas: (1) XOR-swizzled LDS (R3/R4 proved bit-identical; kills the
// 16-way ds_read_b128 conflicts = 7.7e7 extra cyc/dispatch), (2) split-K x2 ->
// grid 1024 + __launch_bounds__(256,4) (occupancy 22%->~45%), (3) single
// repack dispatch for all 3 layers (no chain dependency).

#define PI_F 3.14159265358979323846f

typedef float floatx4 __attribute__((ext_vector_type(4)));
typedef __bf16 bf16x8 __attribute__((ext_vector_type(8)));

// global -> LDS direct DMA, 16B per lane (lane-contiguous dest, per m104/m108).
#define GLOAD_LDS16(gp, lp)                                                    \
  __builtin_amdgcn_global_load_lds(                                            \
      (const __attribute__((address_space(1))) void*)(uintptr_t)(const void*)(gp), \
      (__attribute__((address_space(3))) void*)(uint32_t)(uintptr_t)(void*)(lp),   \
      16, 0, 0)

// ---------------------------------------------------------------------------
// repack body: coeffs (fi,fo,2,65) + alpha (fi,fo) -> Bhi/Blo (fo x Kaug)
static __device__ __forceinline__ void repack_body(
    const float* __restrict__ coeffs, const float* __restrict__ alpha,
    ushort* __restrict__ Bhi, ushort* __restrict__ Blo,
    int fo, int Kaug, int writeLo, int idx, int tid)
{
  int nchunksK = Kaug >> 8;
  int o     = idx / nchunksK;
  int chunk = idx - o * nchunksK;
  int r = chunk * 256 + tid;
  int i = r / 131;
  int j = r - i * 131;
  float v;
  if (j == 130) {
    v = alpha[(size_t)i * fo + o];
  } else {
    int h1 = (j >= 65) ? 1 : 0;
    int d  = j - (h1 ? 65 : 0);
    v = coeffs[(((size_t)i * fo + o) * 2 + h1) * 65 + d];
  }
  __hip_bfloat16 hb = __float2bfloat16(v);
  Bhi[(size_t)o * Kaug + r] = *(ushort*)&hb;
  if (writeLo) {
    __hip_bfloat16 lb = __float2bfloat16(v - __bfloat162float(hb));
    Blo[(size_t)o * Kaug + r] = *(ushort*)&lb;
  }
}

// all-3-layers repack in one dispatch (allB mode)
__global__ __launch_bounds__(256) void repack_all(
    const float* c0, const float* a0, ushort* h0, ushort* l0,
    const float* c1, const float* a1, ushort* h1, ushort* l1,
    const float* c2, const float* a2, ushort* h2,
    int fo0, int fo1, int fo2, int K0, int K1, int K2, int nb0, int nb01)
{
  int b = blockIdx.x, tid = threadIdx.x;
  if (b < nb0)        repack_body(c0, a0, h0, l0, fo0, K0, 1, b,        tid);
  else if (b < nb01)  repack_body(c1, a1, h1, l1, fo1, K1, 1, b - nb0,  tid);
  else                repack_body(c2, a2, h2, 0,  fo2, K2, 0, b - nb01, tid);
}

// per-layer repack (fallback mode)
__global__ __launch_bounds__(256) void repack_kernel(
    const float* __restrict__ coeffs, const float* __restrict__ alpha,
    ushort* __restrict__ Bhi, ushort* __restrict__ Blo,
    int fo, int Kaug, int writeLo)
{
  repack_body(coeffs, alpha, Bhi, Blo, fo, Kaug, writeLo,
              blockIdx.x + blockIdx.y * gridDim.x, threadIdx.x);
}

// ---------------------------------------------------------------------------
// act: Xin (MB x fi) fp32 -> Ahi/Alo (MB x Kaug) bf16 pair, chunk-local.
// Pole-safe sinc: z = {4,8}*tanh(t); n = rint(z), f = z-n (exact);
// sinc(z+kk) = (-1)^(n+kk) * sin(pi f)/(pi (z+kk)).  s carries (-1)^n.
__global__ __launch_bounds__(256) void act_kernel(
    const float* __restrict__ Xin, __hip_bfloat16* __restrict__ Ahi,
    __hip_bfloat16* __restrict__ Alo, int first, int writeLo)
{
  __shared__ float sm[256][5];
  int tid = threadIdx.x;
  int p0  = blockIdx.x * 256;   // first (b,i) pair of this block (chunk-local)
  {
    float x  = Xin[p0 + tid];
    float t  = first ? tanhf(x) : x;   // layer-0 normalizer
    float xa = tanhf(t);
    float z0 = 4.0f * xa, z1 = 8.0f * xa;   // exact (pow2 scale, h=1/4,1/8)
    float n0 = rintf(z0), n1 = rintf(z1);
    float s0 = sinf(PI_F * (z0 - n0)) * (1.0f / PI_F);
    float s1 = sinf(PI_F * (z1 - n1)) * (1.0f / PI_F);
    if (((int)n0) & 1) s0 = -s0;
    if (((int)n1) & 1) s1 = -s1;
    sm[tid][0] = t;
    sm[tid][1] = z0;
    sm[tid][2] = s0;
    sm[tid][3] = z1;
    sm[tid][4] = s1;
  }
  __syncthreads();
  size_t base = (size_t)p0 * 131;
  for (int e = tid; e < 256 * 131; e += 256) {
    int li = e / 131;
    int j  = e - li * 131;
    float t = sm[li][0];
    bool h1 = (j >= 65);
    int d   = h1 ? (j - 65) : j;
    float z = h1 ? sm[li][3] : sm[li][1];
    float s = h1 ? sm[li][4] : sm[li][2];
    int kk  = d - 32;
    float den = z + (float)kk;
    float v = s / den;
    if (kk & 1) v = -v;
    if (den == 0.0f) v = 1.0f;   // sinc(0) = 1 (sign: n=-kk, parity cancels)
    if (j == 130)    v = t;      // skip-connection slot
    __hip_bfloat16 hb = __float2bfloat16(v);
    Ahi[base + e] = hb;
    if (writeLo)
      Alo[base + e] = __float2bfloat16(v - __bfloat162float(hb));
  }
}

// ---------------------------------------------------------------------------
// gemm: C[m,n] = sum over nterms passes of Asel[m,k]*Bsel[n,k]; split-K over
// extended step space S = nterms*totalSteps (term-major).
// term 0: Ahi*Bhi; term 1: Alo*Bhi; term 2: Ahi*Blo.
// 128x128 tile, BK=64, 4 waves (2x2 of 64x64), 16x16x32 MFMA.
// XOR-swizzled LDS: chunk c holds (row=c>>3, kc=(c&7)^(row&7)) -> frag reads
// land 2 lanes/bank (free, m136) instead of 16-way. R3=R4 bit-identical proof.
__global__ __launch_bounds__(256, 4) void gemm_bf16_splitk(
    const __hip_bfloat16* __restrict__ Ahi, const __hip_bfloat16* __restrict__ Alo,
    const __hip_bfloat16* __restrict__ Bhi, const __hip_bfloat16* __restrict__ Blo,
    float* __restrict__ Cpart,              // splitk x MB x N
    int N, int Kaug, int totalSteps, int splitk, int tilesN, int MBN, int nterms)
{
  __shared__ __align__(16) ushort As[128 * 64];
  __shared__ __align__(16) ushort Bs[128 * 64];

  int bx    = blockIdx.x;
  int split = bx % splitk;
  int tile  = bx / splitk;
  int tm = tile / tilesN;
  int tn = tile - tm * tilesN;
  int S  = nterms * totalSteps;
  int s0 = (int)(((long long)split * S) / splitk);
  int s1 = (int)(((long long)(split + 1) * S) / splitk);

  int tid  = threadIdx.x;
  int lane = tid & 63;
  int wave = tid >> 6;
  int wm = (wave >> 1) * 64;
  int wn = (wave & 1) * 64;

  floatx4 acc[4][4];
#pragma unroll
  for (int i = 0; i < 4; i++)
#pragma unroll
    for (int j = 0; j < 4; j++) acc[i][j] = floatx4{0.f, 0.f, 0.f, 0.f};

  for (int term = 0; term < nterms; ++term) {
    int base = term * totalSteps;
    int t0 = s0 - base; if (t0 < 0) t0 = 0;
    int t1 = s1 - base; if (t1 > totalSteps) t1 = totalSteps;
    if (t0 >= t1) continue;

    const ushort* Ag = (const ushort*)((term == 1) ? Alo : Ahi)
                       + (size_t)tm * 128 * Kaug;
    const ushort* Bg = (const ushort*)((term == 2) ? Blo : Bhi)
                       + (size_t)tn * 128 * Kaug;

    for (int s = t0; s < t1; ++s) {
      int k0 = s * 64;
#pragma unroll
      for (int r = 0; r < 4; ++r) {            // stage A tile (128 rows x 64 k)
        int c   = tid + 256 * r;
        int row = c >> 3;
        int kcg = (c & 7) ^ (row & 7);
        GLOAD_LDS16(Ag + (size_t)row * Kaug + k0 + kcg * 8, &As[c * 8]);
      }
#pragma unroll
      for (int r = 0; r < 4; ++r) {            // stage B tile (128 n-rows x 64 k)
        int c   = tid + 256 * r;
        int row = c >> 3;
        int kcg = (c & 7) ^ (row & 7);
        GLOAD_LDS16(Bg + (size_t)row * Kaug + k0 + kcg * 8, &Bs[c * 8]);
      }
      __syncthreads();

#pragma unroll
      for (int q = 0; q < 2; ++q) {             // two K=32 MFMA steps per BK=64
        bf16x8 af[4], bf[4];
        int rsub = lane & 15;
        int qc   = q * 4 + (lane >> 4);
#pragma unroll
        for (int t = 0; t < 4; ++t) {
          int row = wm + t * 16 + rsub;
          af[t] = *(const bf16x8*)&As[(row * 8 + (qc ^ (row & 7))) * 8];
        }
#pragma unroll
        for (int t = 0; t < 4; ++t) {
          int row = wn + t * 16 + rsub;
          bf[t] = *(const bf16x8*)&Bs[(row * 8 + (qc ^ (row & 7))) * 8];
        }
#pragma unroll
        for (int i = 0; i < 4; ++i)
#pragma unroll
          for (int j = 0; j < 4; ++j)
            acc[i][j] = __builtin_amdgcn_mfma_f32_16x16x32_bf16(
                af[i], bf[j], acc[i][j], 0, 0, 0);
      }
      __syncthreads();
    }
  }

  // epilogue: C/D layout col = lane&15, row = (lane>>4)*4 + reg  [m89-verified]
  float* Cp = Cpart + (size_t)split * MBN;
  int mrow0 = tm * 128 + wm + (lane >> 4) * 4;
  int ncol  = tn * 128 + wn + (lane & 15);
#pragma unroll
  for (int i = 0; i < 4; ++i) {
#pragma unroll
    for (int r = 0; r < 4; ++r) {
      int m = mrow0 + i * 16 + r;
      float* dst = Cp + (size_t)m * N + ncol;
#pragma unroll
      for (int j = 0; j < 4; ++j) dst[j * 16] = acc[i][j][r];
    }
  }
}

// ---------------------------------------------------------------------------
// reduce split-K partials + beta -> fp32 (intermediate layers AND final out)
__global__ __launch_bounds__(256) void reduce_f32_kernel(
    const float4* __restrict__ Cp, const float* __restrict__ beta,
    float* __restrict__ Xout, int MN4, int N4mask, int splits)
{
  int e = blockIdx.x * 256 + threadIdx.x;
  if (e >= MN4) return;
  float4 sum = Cp[e];
  for (int s = 1; s < splits; ++s) {
    float4 v = Cp[(size_t)s * MN4 + e];
    sum.x += v.x; sum.y += v.y; sum.z += v.z; sum.w += v.w;
  }
  int n0 = (e & N4mask) * 4;
  sum.x += beta[n0]; sum.y += beta[n0 + 1];
  sum.z += beta[n0 + 2]; sum.w += beta[n0 + 3];
  ((float4*)Xout)[e] = sum;
}

// ---------------------------------------------------------------------------
extern "C" void kernel_launch(void* const* d_in, const int* in_sizes, int n_in,
                              void* d_out, int out_size, void* d_ws, size_t ws_size,
                              hipStream_t stream)
{
  const float* x = (const float*)d_in[0];
  const float* coeffs[3] = {(const float*)d_in[1], (const float*)d_in[4], (const float*)d_in[7]};
  const float* alpha[3]  = {(const float*)d_in[2], (const float*)d_in[5], (const float*)d_in[8]};
  const float* beta[3]   = {(const float*)d_in[3], (const float*)d_in[6], (const float*)d_in[9]};

  const int fis[3] = {256, 512, 512};
  const int fos[3] = {512, 512, 256};
  const int trm[3] = {3, 3, 1};     // split-bf16 for layers 0,1; plain for 2

  const size_t KMAX = 67072;        // 512*131
  // all-layer B sizes (bytes): L0 hi+lo, L1 hi+lo, L2 hi
  const size_t bsz[3] = {2ull * 512 * 33536 * 2, 2ull * 512 * 67072 * 2,
                         1ull * 256 * 67072 * 2};
  const size_t Ball   = bsz[0] + bsz[1] + bsz[2];       // 240,386,048
  const size_t B1     = 2ull * 512 * KMAX * 2;          // 137,363,456 (max single)
  const size_t needX  = 2ull * 1024 * 512 * 4;          // 4 MB

  // deterministic mode ladder from ws_size only
  int MB = 1024, allB = 0;
  size_t cbytes = 67108864;
  for (;;) {
    size_t aB = (size_t)MB * KMAX * 4;
    if (aB + Ball + needX + 67108864 <= ws_size) { allB = 1; cbytes = 67108864; break; }
    if (aB + B1 + needX + 67108864 <= ws_size)   { allB = 0; cbytes = 67108864; break; }
    if (aB + B1 + needX + 33554432 <= ws_size)   { allB = 0; cbytes = 33554432; break; }
    if (MB == 128) { allB = 0; cbytes = 33554432; break; }
    MB >>= 1;
  }
  int nchunks = 1024 / MB;

  char* ws = (char*)d_ws;
  __hip_bfloat16* Ahi = (__hip_bfloat16*)ws;
  __hip_bfloat16* Alo = Ahi + (size_t)MB * KMAX;
  char* Bbase = ws + (size_t)MB * KMAX * 4;
  // per-layer B pointers
  ushort* Bh[3]; ushort* Bl[3];
  if (allB) {
    char* p = Bbase;
    for (int l = 0; l < 3; ++l) {
      Bh[l] = (ushort*)p;
      Bl[l] = (trm[l] > 1) ? (ushort*)(p + bsz[l] / 2) : 0;
      p += bsz[l];
    }
  } else {
    for (int l = 0; l < 3; ++l) {
      Bh[l] = (ushort*)Bbase;
      Bl[l] = (trm[l] > 1) ? (ushort*)(Bbase + B1 / 2) : 0;
    }
  }
  size_t bTot = allB ? Ball : B1;
  float* X1    = (float*)(Bbase + bTot);
  float* X2    = X1 + 1024 * 512;
  float* Cpart = X2 + 1024 * 512;

  if (allB) {
    int nb0 = (33536 / 256) * 512;        // 67,072 blocks
    int nb1 = (67072 / 256) * 512;        // 134,144
    int nb2 = (67072 / 256) * 256;        // 67,072
    repack_all<<<nb0 + nb1 + nb2, 256, 0, stream>>>(
        coeffs[0], alpha[0], Bh[0], Bl[0],
        coeffs[1], alpha[1], Bh[1], Bl[1],
        coeffs[2], alpha[2], Bh[2],
        fos[0], fos[1], fos[2], 33536, 67072, 67072, nb0, nb0 + nb1);
  }

  const float* Xl = x;
  for (int l = 0; l < 3; ++l) {
    int fi = fis[l], fo = fos[l];
    int Kaug = fi * 131;            // 33536 / 67072 — divisible by 256
    int totalSteps = Kaug / 64;
    int tilesN = fo / 128;
    int sk = (int)(cbytes / 4 / ((size_t)MB * fo));
    if (sk < 1) sk = 1;
    int nterms = trm[l];

    if (!allB) {
      repack_kernel<<<dim3(Kaug / 256, fo), 256, 0, stream>>>(
          coeffs[l], alpha[l], Bh[l], Bl[l], fo, Kaug, nterms > 1 ? 1 : 0);
    }

    float* Xout_f = (l == 0) ? X1 : (l == 1 ? X2 : (float*)d_out);
    for (int c = 0; c < nchunks; ++c) {
      int mb0 = c * MB;
      act_kernel<<<(MB * fi) / 256, 256, 0, stream>>>(
          Xl + (size_t)mb0 * fi, Ahi, Alo, l == 0 ? 1 : 0, nterms > 1 ? 1 : 0);
      gemm_bf16_splitk<<<(MB / 128) * tilesN * sk, 256, 0, stream>>>(
          (const __hip_bfloat16*)Ahi, (const __hip_bfloat16*)Alo,
          (const __hip_bfloat16*)Bh[l], (const __hip_bfloat16*)Bl[l],
          Cpart, fo, Kaug, totalSteps, sk, tilesN, MB * fo, nterms);
      int MN4 = MB * fo / 4;
      reduce_f32_kernel<<<(MN4 + 255) / 256, 256, 0, stream>>>(
          (const float4*)Cpart, beta[l],
          Xout_f + (size_t)mb0 * fo, MN4, fo / 4 - 1, sk);
    }
    Xl = Xout_f;
  }
}

// Round 8
// 1072.773 us; speedup vs baseline: 1.1070x; 1.0184x over previous
//
#include <hip/hip_runtime.h>
#include <hip/hip_bf16.h>
#include <cstdint>

// sincKAN: 3 layers. B=1024, features 256->512->512->256, LEN_H=2, DEGREE+1=65.
// Kaug = fi*131 (per input i: h0 d0..64 | h1 d0..64 | skip slot = x_i).
// Split-bf16 (hi/lo): acc += Ahi*Bhi + Ahi*Blo + Alo*Bhi (layers 0,1);
// layer 2 hi-only. PASSED R6/R7 @ absmax 2.09.
// R8: ONE-PASS gemm — stage all 4 operands per K-step (BK=32, 32KB LDS),
// 48 MFMA/step into shared acc (1.5x MFMA:staging & MFMA:barrier density;
// halves logical A-hi/B-hi traffic). New BK=32 swizzle x(row)=(row&3)^((row>>2)&3)
// (row stride 64B = half bank period; verified <=2 lanes/bank-group).
// act: ushort4 stores + __fdividef.

#define PI_F 3.14159265358979323846f

typedef float floatx4 __attribute__((ext_vector_type(4)));
typedef __bf16 bf16x8 __attribute__((ext_vector_type(8)));

// global -> LDS direct DMA, 16B per lane (lane-contiguous dest, per m104/m108).
#define GLOAD_LDS16(gp, lp)                                                    \
  __builtin_amdgcn_global_load_lds(                                            \
      (const __attribute__((address_space(1))) void*)(uintptr_t)(const void*)(gp), \
      (__attribute__((address_space(3))) void*)(uint32_t)(uintptr_t)(void*)(lp),   \
      16, 0, 0)

// ---------------------------------------------------------------------------
// repack body: coeffs (fi,fo,2,65) + alpha (fi,fo) -> Bhi/Blo (fo x Kaug)
static __device__ __forceinline__ void repack_body(
    const float* __restrict__ coeffs, const float* __restrict__ alpha,
    ushort* __restrict__ Bhi, ushort* __restrict__ Blo,
    int fo, int Kaug, int writeLo, int idx, int tid)
{
  int nchunksK = Kaug >> 8;
  int o     = idx / nchunksK;
  int chunk = idx - o * nchunksK;
  int r = chunk * 256 + tid;
  int i = r / 131;
  int j = r - i * 131;
  float v;
  if (j == 130) {
    v = alpha[(size_t)i * fo + o];
  } else {
    int h1 = (j >= 65) ? 1 : 0;
    int d  = j - (h1 ? 65 : 0);
    v = coeffs[(((size_t)i * fo + o) * 2 + h1) * 65 + d];
  }
  __hip_bfloat16 hb = __float2bfloat16(v);
  Bhi[(size_t)o * Kaug + r] = *(ushort*)&hb;
  if (writeLo) {
    __hip_bfloat16 lb = __float2bfloat16(v - __bfloat162float(hb));
    Blo[(size_t)o * Kaug + r] = *(ushort*)&lb;
  }
}

// all-3-layers repack in one dispatch (allB mode)
__global__ __launch_bounds__(256) void repack_all(
    const float* c0, const float* a0, ushort* h0, ushort* l0,
    const float* c1, const float* a1, ushort* h1, ushort* l1,
    const float* c2, const float* a2, ushort* h2,
    int fo0, int fo1, int fo2, int K0, int K1, int K2, int nb0, int nb01)
{
  int b = blockIdx.x, tid = threadIdx.x;
  if (b < nb0)        repack_body(c0, a0, h0, l0, fo0, K0, 1, b,        tid);
  else if (b < nb01)  repack_body(c1, a1, h1, l1, fo1, K1, 1, b - nb0,  tid);
  else                repack_body(c2, a2, h2, 0,  fo2, K2, 0, b - nb01, tid);
}

// per-layer repack (fallback mode)
__global__ __launch_bounds__(256) void repack_kernel(
    const float* __restrict__ coeffs, const float* __restrict__ alpha,
    ushort* __restrict__ Bhi, ushort* __restrict__ Blo,
    int fo, int Kaug, int writeLo)
{
  repack_body(coeffs, alpha, Bhi, Blo, fo, Kaug, writeLo,
              blockIdx.x + blockIdx.y * gridDim.x, threadIdx.x);
}

// ---------------------------------------------------------------------------
// act: Xin (MB x fi) fp32 -> Ahi/Alo (MB x Kaug) bf16 pair, chunk-local.
// Pole-safe sinc: z = {4,8}*tanh(t); n = rint(z), f = z-n (exact);
// sinc(z+kk) = (-1)^(n+kk) * sin(pi f)/(pi (z+kk)).  s carries (-1)^n.
// ushort4 (8B) vectorized stores: thread handles 4 consecutive flat taps.
__global__ __launch_bounds__(256) void act_kernel(
    const float* __restrict__ Xin, ushort* __restrict__ Ahi,
    ushort* __restrict__ Alo, int first, int writeLo)
{
  __shared__ float sm[256][5];
  int tid = threadIdx.x;
  int p0  = blockIdx.x * 256;   // first (b,i) pair of this block (chunk-local)
  {
    float x  = Xin[p0 + tid];
    float t  = first ? tanhf(x) : x;   // layer-0 normalizer
    float xa = tanhf(t);
    float z0 = 4.0f * xa, z1 = 8.0f * xa;   // exact (pow2 scale, h=1/4,1/8)
    float n0 = rintf(z0), n1 = rintf(z1);
    float s0 = sinf(PI_F * (z0 - n0)) * (1.0f / PI_F);
    float s1 = sinf(PI_F * (z1 - n1)) * (1.0f / PI_F);
    if (((int)n0) & 1) s0 = -s0;
    if (((int)n1) & 1) s1 = -s1;
    sm[tid][0] = t;
    sm[tid][1] = z0;
    sm[tid][2] = s0;
    sm[tid][3] = z1;
    sm[tid][4] = s1;
  }
  __syncthreads();
  size_t base = (size_t)p0 * 131;           // multiple of 4 (256*131*blk)
  for (int e4 = tid; e4 < 64 * 131; e4 += 256) {   // 131*256/4 quads
    int f0 = e4 * 4;
    ushort4 hv, lv;
#pragma unroll
    for (int u = 0; u < 4; ++u) {
      int f  = f0 + u;
      int li = f / 131;
      int j  = f - li * 131;
      float t = sm[li][0];
      bool h1 = (j >= 65);
      int d   = h1 ? (j - 65) : j;
      float z = h1 ? sm[li][3] : sm[li][1];
      float s = h1 ? sm[li][4] : sm[li][2];
      int kk  = d - 32;
      float den = z + (float)kk;
      float v = __fdividef(s, den);
      if (kk & 1) v = -v;
      if (den == 0.0f) v = 1.0f;   // sinc(0) = 1 (sign: n=-kk, parity cancels)
      if (j == 130)    v = t;      // skip-connection slot
      __hip_bfloat16 hb = __float2bfloat16(v);
      __hip_bfloat16 lb = __float2bfloat16(v - __bfloat162float(hb));
      ((ushort*)&hv)[u] = *(ushort*)&hb;
      ((ushort*)&lv)[u] = *(ushort*)&lb;
    }
    *(ushort4*)(Ahi + base + f0) = hv;
    if (writeLo) *(ushort4*)(Alo + base + f0) = lv;
  }
}

// ---------------------------------------------------------------------------
// gemm one-pass: C[m,n] = sum_k Ahi*Bhi + Ahi*Blo + Alo*Bhi (nterms=3) or
// Ahi*Bhi (nterms=1); split-K partials. 128x128 tile, BK=32, 4 waves,
// 16x16x32 MFMA. All operands staged per step; shared accumulator.
// Swizzle: LDS chunk (row, cc) holds global (row, cc ^ x(row)),
// x(row) = (row&3)^((row>>2)&3). Frag read: chunk = row*4 + (qc ^ x(row)).
__global__ __launch_bounds__(256, 4) void gemm_bf16_onepass(
    const ushort* __restrict__ Ahi, const ushort* __restrict__ Alo,
    const ushort* __restrict__ Bhi, const ushort* __restrict__ Blo,
    float* __restrict__ Cpart,              // splitk x MB x N
    int N, int Kaug, int T, int splitk, int tilesN, int MBN, int nterms)
{
  __shared__ __align__(16) ushort AsH[128 * 32];
  __shared__ __align__(16) ushort AsL[128 * 32];
  __shared__ __align__(16) ushort BsH[128 * 32];
  __shared__ __align__(16) ushort BsL[128 * 32];

  int bx    = blockIdx.x;
  int split = bx % splitk;
  int tile  = bx / splitk;
  int tm = tile / tilesN;
  int tn = tile - tm * tilesN;
  int s0 = (int)(((long long)split * T) / splitk);
  int s1 = (int)(((long long)(split + 1) * T) / splitk);

  int tid  = threadIdx.x;
  int lane = tid & 63;
  int wave = tid >> 6;
  int wm = (wave >> 1) * 64;
  int wn = (wave & 1) * 64;

  floatx4 acc[4][4];
#pragma unroll
  for (int i = 0; i < 4; i++)
#pragma unroll
    for (int j = 0; j < 4; j++) acc[i][j] = floatx4{0.f, 0.f, 0.f, 0.f};

  const ushort* AgH = Ahi + (size_t)tm * 128 * Kaug;
  const ushort* AgL = Alo + (size_t)tm * 128 * Kaug;
  const ushort* BgH = Bhi + (size_t)tn * 128 * Kaug;
  const ushort* BgL = Blo + (size_t)tn * 128 * Kaug;

  // frag LDS byte offsets (hoisted; H/L share offsets, different buffers)
  int rsub = lane & 15;
  int qc   = lane >> 4;
  int aoff[4], boff[4];
#pragma unroll
  for (int t = 0; t < 4; ++t) {
    int ra = wm + t * 16 + rsub;
    aoff[t] = (ra * 4 + (qc ^ (ra & 3) ^ ((ra >> 2) & 3))) * 8;
    int rb = wn + t * 16 + rsub;
    boff[t] = (rb * 4 + (qc ^ (rb & 3) ^ ((rb >> 2) & 3))) * 8;
  }

  for (int s = s0; s < s1; ++s) {
    int k0 = s * 32;
#pragma unroll
    for (int r = 0; r < 2; ++r) {           // 512 chunks per tile, 2 iters
      int c   = tid + 256 * r;
      int row = c >> 2;
      int cc  = c & 3;
      int kcg = cc ^ (row & 3) ^ ((row >> 2) & 3);
      size_t goff = (size_t)row * Kaug + k0 + kcg * 8;
      GLOAD_LDS16(AgH + goff, &AsH[c * 8]);
      GLOAD_LDS16(BgH + goff, &BsH[c * 8]);
      if (nterms > 1) {
        GLOAD_LDS16(AgL + goff, &AsL[c * 8]);
        GLOAD_LDS16(BgL + goff, &BsL[c * 8]);
      }
    }
    __syncthreads();

    bf16x8 ah[4], bh[4];
#pragma unroll
    for (int t = 0; t < 4; ++t) ah[t] = *(const bf16x8*)&AsH[aoff[t]];
#pragma unroll
    for (int t = 0; t < 4; ++t) bh[t] = *(const bf16x8*)&BsH[boff[t]];
#pragma unroll
    for (int i = 0; i < 4; ++i)
#pragma unroll
      for (int j = 0; j < 4; ++j)
        acc[i][j] = __builtin_amdgcn_mfma_f32_16x16x32_bf16(
            ah[i], bh[j], acc[i][j], 0, 0, 0);

    if (nterms > 1) {
      bf16x8 bl[4];
#pragma unroll
      for (int t = 0; t < 4; ++t) bl[t] = *(const bf16x8*)&BsL[boff[t]];
#pragma unroll
      for (int i = 0; i < 4; ++i)
#pragma unroll
        for (int j = 0; j < 4; ++j)
          acc[i][j] = __builtin_amdgcn_mfma_f32_16x16x32_bf16(
              ah[i], bl[j], acc[i][j], 0, 0, 0);
      bf16x8 al[4];
#pragma unroll
      for (int t = 0; t < 4; ++t) al[t] = *(const bf16x8*)&AsL[aoff[t]];
#pragma unroll
      for (int i = 0; i < 4; ++i)
#pragma unroll
        for (int j = 0; j < 4; ++j)
          acc[i][j] = __builtin_amdgcn_mfma_f32_16x16x32_bf16(
              al[i], bh[j], acc[i][j], 0, 0, 0);
    }
    __syncthreads();
  }

  // epilogue: C/D layout col = lane&15, row = (lane>>4)*4 + reg  [m89-verified]
  float* Cp = Cpart + (size_t)split * MBN;
  int mrow0 = tm * 128 + wm + (lane >> 4) * 4;
  int ncol  = tn * 128 + wn + (lane & 15);
#pragma unroll
  for (int i = 0; i < 4; ++i) {
#pragma unroll
    for (int r = 0; r < 4; ++r) {
      int m = mrow0 + i * 16 + r;
      float* dst = Cp + (size_t)m * N + ncol;
#pragma unroll
      for (int j = 0; j < 4; ++j) dst[j * 16] = acc[i][j][r];
    }
  }
}

// ---------------------------------------------------------------------------
// reduce split-K partials + beta -> fp32 (intermediate layers AND final out)
__global__ __launch_bounds__(256) void reduce_f32_kernel(
    const float4* __restrict__ Cp, const float* __restrict__ beta,
    float* __restrict__ Xout, int MN4, int N4mask, int splits)
{
  int e = blockIdx.x * 256 + threadIdx.x;
  if (e >= MN4) return;
  float4 sum = Cp[e];
  for (int s = 1; s < splits; ++s) {
    float4 v = Cp[(size_t)s * MN4 + e];
    sum.x += v.x; sum.y += v.y; sum.z += v.z; sum.w += v.w;
  }
  int n0 = (e & N4mask) * 4;
  sum.x += beta[n0]; sum.y += beta[n0 + 1];
  sum.z += beta[n0 + 2]; sum.w += beta[n0 + 3];
  ((float4*)Xout)[e] = sum;
}

// ---------------------------------------------------------------------------
extern "C" void kernel_launch(void* const* d_in, const int* in_sizes, int n_in,
                              void* d_out, int out_size, void* d_ws, size_t ws_size,
                              hipStream_t stream)
{
  const float* x = (const float*)d_in[0];
  const float* coeffs[3] = {(const float*)d_in[1], (const float*)d_in[4], (const float*)d_in[7]};
  const float* alpha[3]  = {(const float*)d_in[2], (const float*)d_in[5], (const float*)d_in[8]};
  const float* beta[3]   = {(const float*)d_in[3], (const float*)d_in[6], (const float*)d_in[9]};

  const int fis[3] = {256, 512, 512};
  const int fos[3] = {512, 512, 256};
  const int trm[3] = {3, 3, 1};     // split-bf16 for layers 0,1; plain for 2

  const size_t KMAX = 67072;        // 512*131
  const size_t bsz[3] = {2ull * 512 * 33536 * 2, 2ull * 512 * 67072 * 2,
                         1ull * 256 * 67072 * 2};
  const size_t Ball   = bsz[0] + bsz[1] + bsz[2];       // 240,386,048
  const size_t B1     = 2ull * 512 * KMAX * 2;          // 137,363,456 (max single)
  const size_t needX  = 2ull * 1024 * 512 * 4;          // 4 MB

  // deterministic mode ladder from ws_size only
  int MB = 1024, allB = 0;
  size_t cbytes = 67108864;
  for (;;) {
    size_t aB = (size_t)MB * KMAX * 4;
    if (aB + Ball + needX + 67108864 <= ws_size) { allB = 1; cbytes = 67108864; break; }
    if (aB + B1 + needX + 67108864 <= ws_size)   { allB = 0; cbytes = 67108864; break; }
    if (aB + B1 + needX + 33554432 <= ws_size)   { allB = 0; cbytes = 33554432; break; }
    if (MB == 128) { allB = 0; cbytes = 33554432; break; }
    MB >>= 1;
  }
  int nchunks = 1024 / MB;

  char* ws = (char*)d_ws;
  ushort* Ahi = (ushort*)ws;
  ushort* Alo = Ahi + (size_t)MB * KMAX;
  char* Bbase = ws + (size_t)MB * KMAX * 4;
  ushort* Bh[3]; ushort* Bl[3];
  if (allB) {
    char* p = Bbase;
    for (int l = 0; l < 3; ++l) {
      Bh[l] = (ushort*)p;
      Bl[l] = (trm[l] > 1) ? (ushort*)(p + bsz[l] / 2) : (ushort*)p;
      p += bsz[l];
    }
  } else {
    for (int l = 0; l < 3; ++l) {
      Bh[l] = (ushort*)Bbase;
      Bl[l] = (trm[l] > 1) ? (ushort*)(Bbase + B1 / 2) : (ushort*)Bbase;
    }
  }
  size_t bTot = allB ? Ball : B1;
  float* X1    = (float*)(Bbase + bTot);
  float* X2    = X1 + 1024 * 512;
  float* Cpart = X2 + 1024 * 512;

  if (allB) {
    int nb0 = (33536 / 256) * 512;
    int nb1 = (67072 / 256) * 512;
    int nb2 = (67072 / 256) * 256;
    repack_all<<<nb0 + nb1 + nb2, 256, 0, stream>>>(
        coeffs[0], alpha[0], Bh[0], Bl[0],
        coeffs[1], alpha[1], Bh[1], Bl[1],
        coeffs[2], alpha[2], Bh[2],
        fos[0], fos[1], fos[2], 33536, 67072, 67072, nb0, nb0 + nb1);
  }

  const float* Xl = x;
  for (int l = 0; l < 3; ++l) {
    int fi = fis[l], fo = fos[l];
    int Kaug = fi * 131;            // 33536 / 67072 — divisible by 256
    int T = Kaug / 32;              // BK=32 steps
    int tilesN = fo / 128;
    int sk = (int)(cbytes / 4 / ((size_t)MB * fo));
    if (sk < 1) sk = 1;
    int nterms = trm[l];

    if (!allB) {
      repack_kernel<<<dim3(Kaug / 256, fo), 256, 0, stream>>>(
          coeffs[l], alpha[l], Bh[l], Bl[l], fo, Kaug, nterms > 1 ? 1 : 0);
    }

    float* Xout_f = (l == 0) ? X1 : (l == 1 ? X2 : (float*)d_out);
    for (int c = 0; c < nchunks; ++c) {
      int mb0 = c * MB;
      act_kernel<<<(MB * fi) / 256, 256, 0, stream>>>(
          Xl + (size_t)mb0 * fi, Ahi, Alo, l == 0 ? 1 : 0, nterms > 1 ? 1 : 0);
      gemm_bf16_onepass<<<(MB / 128) * tilesN * sk, 256, 0, stream>>>(
          Ahi, (nterms > 1) ? Alo : Ahi, Bh[l], Bl[l],
          Cpart, fo, Kaug, T, sk, tilesN, MB * fo, nterms);
      int MN4 = MB * fo / 4;
      reduce_f32_kernel<<<(MN4 + 255) / 256, 256, 0, stream>>>(
          (const float4*)Cpart, beta[l],
          Xout_f + (size_t)mb0 * fo, MN4, fo / 4 - 1, sk);
    }
    Xl = Xout_f;
  }
}